// Round 5
// baseline (147.882 us; speedup 1.0000x reference)
//
#include <hip/hip_runtime.h>
#include <math.h>

// Problem constants (fixed by the reference)
#define N_NODES 50000
#define N_EDGES 800000
#define FN_DIM 16
#define HD 64
#define T_CAP 8192     // cap on |need1| (expected ~355)  = layer-0 targets
#define T2_CAP 512     // cap on |need2| (expected ~17)   = layer-1 targets
#define MAXDEG 128     // cap on in-degree (Poisson(16))

// small-vector LDS slots
#define SV_BC1 0
#define SV_BC2 64
#define SV_BG  128
#define SV_PS  192
#define SV_PD  256
#define SV_BN  320
#define SV_GN  384
#define SV_BETAN 448

// ---------- wave-64 helpers ----------
__device__ __forceinline__ float wsum64(float v) {
    #pragma unroll
    for (int o = 1; o < 64; o <<= 1) v += __shfl_xor(v, o);
    return v;
}
__device__ __forceinline__ float lrelu02(float v) { return v > 0.f ? v : 0.2f * v; }

// ---------- zero the flag/counter zone ----------
__global__ void k_zero(int4* __restrict__ p, int n4) {
    int i = blockIdx.x * blockDim.x + threadIdx.x;
    if (i < n4) p[i] = make_int4(0, 0, 0, 0);
}

// ---------- discovery (int4-vectorized, 4 edges/thread) ----------
__global__ void k_mark2(const int* __restrict__ ei, int* need1, int* need2) {
    int i = blockIdx.x * blockDim.x + threadIdx.x;
    if (i == 0) { need1[0] = 1; need2[0] = 1; }
    if (i >= N_EDGES / 4) return;
    int4 d4 = ((const int4*)(ei + N_EDGES))[i];
    int4 s4 = ((const int4*)ei)[i];
    if (d4.x == 0) { need2[s4.x] = 1; need1[s4.x] = 1; }
    if (d4.y == 0) { need2[s4.y] = 1; need1[s4.y] = 1; }
    if (d4.z == 0) { need2[s4.z] = 1; need1[s4.z] = 1; }
    if (d4.w == 0) { need2[s4.w] = 1; need1[s4.w] = 1; }
}
__global__ void k_mark1(const int* __restrict__ ei, const int* __restrict__ need2, int* need1) {
    int i = blockIdx.x * blockDim.x + threadIdx.x;
    if (i >= N_EDGES / 4) return;
    int4 d4 = ((const int4*)(ei + N_EDGES))[i];
    int4 s4 = ((const int4*)ei)[i];
    if (need2[d4.x]) need1[s4.x] = 1;
    if (need2[d4.y]) need1[s4.y] = 1;
    if (need2[d4.z]) need1[s4.z] = 1;
    if (need2[d4.w]) need1[s4.w] = 1;
}

// ---------- compact node lists + idx maps; blocks 0..5 also compute ps/pd vecs ----------
__global__ void k_compact(const int* __restrict__ need1, const int* __restrict__ need2,
                          int* list1, int* list2, int* idx1, int* idx2, int* cnt,
                          const float* __restrict__ Wg, const float* __restrict__ atts,
                          const float* __restrict__ attd, float* __restrict__ pvec) {
    int i = blockIdx.x * blockDim.x + threadIdx.x;
    if (i < N_NODES) {
        if (need1[i]) { int p = atomicAdd(&cnt[0], 1); if (p < T_CAP)  { list1[p] = i; idx1[i] = p; } }
        if (need2[i]) { int p = atomicAdd(&cnt[1], 1); if (p < T2_CAP) { list2[p] = i; idx2[i] = p; } }
    }
    // ps[l] = Wg[l]^T att_src[l], pd[l] = Wg[l]^T att_dst[l]
    if (blockIdx.x < 6 && threadIdx.x < 64) {
        int task = blockIdx.x; int l = task >> 1; int which = task & 1;
        const float* att = which ? attd : atts;
        float av = att[l * 64 + threadIdx.x];
        const float* wg = Wg + l * 4096 + threadIdx.x * 64;
        float acc = 0.f;
        #pragma unroll 8
        for (int c = 0; c < 64; c++) acc += wg[c] * __shfl(av, c);
        pvec[l * 128 + which * 64 + threadIdx.x] = acc;
    }
}

__global__ void k_bucket(const int* __restrict__ ei, const int* __restrict__ need1,
                         const int* __restrict__ need2,
                         const int* __restrict__ idx1, const int* __restrict__ idx2,
                         int* eb1, int* deg1, int* eb2, int* deg2, int* eb3, int* deg3) {
    int i = blockIdx.x * blockDim.x + threadIdx.x;
    if (i >= N_EDGES / 4) return;
    int4 d4 = ((const int4*)(ei + N_EDGES))[i];
    int4 s4 = ((const int4*)ei)[i];
    int ds[4] = {d4.x, d4.y, d4.z, d4.w};
    int ss[4] = {s4.x, s4.y, s4.z, s4.w};
    #pragma unroll
    for (int c = 0; c < 4; c++) {
        int d = ds[c], s = ss[c];
        if (need1[d]) {
            int t = idx1[d];
            if ((unsigned)t < T_CAP) { int p = atomicAdd(&deg1[t], 1); if (p < MAXDEG) eb1[t * MAXDEG + p] = s; }
        }
        if (need2[d]) {
            int t = idx2[d];
            if ((unsigned)t < T2_CAP) { int p = atomicAdd(&deg2[t], 1); if (p < MAXDEG) eb2[t * MAXDEG + p] = s; }
        }
        if (d == 0) { int p = atomicAdd(deg3, 1); if (p < MAXDEG) eb3[p] = s; }
    }
}

// ---------- fused layer, latency-optimized ----------
// Per block: stage Wc1b/Wc2/(Wn) in LDS once (float4). Per target:
//  - every wave redundantly computes target feature (1 concurrent gather + LDS math)
//  - u = Wc1a.h_t k-split across 4 waves (16 unrolled global loads each -> 1 wait)
//  - edges 4-per-wave-per-pass: concurrent gathers, LDS-weight matvecs, online softmax in regs
//  - att = Wg.hbar k-split across 4 waves
template<int LM>
__global__ __launch_bounds__(256, 1) void k_layer(
    const float* __restrict__ x, const float* __restrict__ Wn, const float* __restrict__ bn,
    const float* __restrict__ gn, const float* __restrict__ betan,
    const float* __restrict__ hin,
    const float* __restrict__ Wc1, const float* __restrict__ bc1,
    const float* __restrict__ Wc2, const float* __restrict__ bc2,
    const float* __restrict__ Wg, const float* __restrict__ pvec,
    const float* __restrict__ bgv,
    const int* __restrict__ tlist, const int* __restrict__ cntp, int tcap,
    const int* __restrict__ eb, const int* __restrict__ deg,
    float* __restrict__ hout,
    const float* __restrict__ Wq1, const float* __restrict__ bq1,
    const float* __restrict__ gq, const float* __restrict__ betaq,
    const float* __restrict__ Wq2, const float* __restrict__ bq2,
    const float* __restrict__ Wv1, const float* __restrict__ bv1,
    const float* __restrict__ gv, const float* __restrict__ betav,
    const float* __restrict__ Wv2, const float* __restrict__ bv2)
{
    __shared__ float wB[HD * HD];     // Wc1 rows 64..127 (source half)
    __shared__ float wC[HD * HD];     // Wc2
    __shared__ float wN[FN_DIM * HD]; // Wn (LM0)
    __shared__ float sv[8 * 64];
    __shared__ float redU[4][HD];
    __shared__ float redA[4][HD];
    __shared__ float redH[4][HD];
    __shared__ float sM[4], sW[4];
    __shared__ float sHbar[HD];

    int tid = threadIdx.x;
    int lane = tid & 63;
    int wv = tid >> 6;

    // ---- stage weights (all loads independent)
    for (int i = tid; i < 1024; i += 256) ((float4*)wB)[i] = ((const float4*)(Wc1 + 4096))[i];
    for (int i = tid; i < 1024; i += 256) ((float4*)wC)[i] = ((const float4*)Wc2)[i];
    if (LM == 0) { if (tid < 256) ((float4*)wN)[tid] = ((const float4*)Wn)[tid]; }
    {
        int a = wv, l = lane;
        if (a == 0) sv[SV_BC1 + l] = bc1[l];
        else if (a == 1) sv[SV_BC2 + l] = bc2[l];
        else if (a == 2) sv[SV_BG + l] = bgv[l];
        else sv[SV_PS + l] = pvec[l];
        if (a == 0) sv[SV_PD + l] = pvec[64 + l];
        else if (LM == 0) {
            if (a == 1) sv[SV_BN + l] = bn[l];
            else if (a == 2) sv[SV_GN + l] = gn[l];
            else sv[SV_BETAN + l] = betan[l];
        }
    }
    __syncthreads();

    int ntgt = (LM == 2) ? 1 : min(cntp[0], tcap);

    for (int w = blockIdx.x; w < ntgt; w += gridDim.x) {
        int t = (LM == 2) ? 0 : tlist[w];
        int dg = deg[(LM == 2) ? 0 : w]; if (dg > MAXDEG) dg = MAXDEG;
        const int* ebrow = eb + (size_t)((LM == 2) ? 0 : w) * MAXDEG;

        // ---- target feature (redundant per wave; 1 concurrent gather)
        float hval;
        if (LM == 0) {
            float xv = x[t * FN_DIM + (lane & 15)];
            float acc = sv[SV_BN + lane];
            #pragma unroll
            for (int k = 0; k < FN_DIM; k++) acc += __shfl(xv, k) * wN[k * HD + lane];
            float vv = fmaxf(acc, 0.f);
            float mu = wsum64(vv) * (1.f / 64.f);
            float dd = vv - mu;
            float var = wsum64(dd * dd) * (1.f / 64.f);
            hval = dd * rsqrtf(var + 1e-5f) * sv[SV_GN + lane] + sv[SV_BETAN + lane];
        } else {
            hval = hin[t * HD + lane];
        }
        float a_st = wsum64(hval * sv[SV_PS + lane]);
        float a_dt = wsum64(hval * sv[SV_PD + lane]);
        float es = lrelu02(a_st + a_dt);   // self-loop logit

        // ---- u = bc1 + Wc1a.h_t, k-split (16 unrolled global loads per wave)
        float up = 0.f;
        #pragma unroll
        for (int kk = 0; kk < 16; kk++) {
            int k = (wv << 4) + kk;
            up += __shfl(hval, k) * Wc1[k * HD + lane];
        }
        redU[wv][lane] = up;
        __syncthreads();
        float uval = sv[SV_BC1 + lane] + redU[0][lane] + redU[1][lane]
                   + redU[2][lane] + redU[3][lane];

        // ---- edge phase: 4 edges per wave per pass, online softmax in registers
        float aggw = -INFINITY, mrun = -INFINITY, wpart = 0.f, hw = 0.f;
        for (int base = wv * 4; base < dg; base += 16) {
            int ne = dg - base; if (ne > 4) ne = 4;
            int4 e4 = *(const int4*)(ebrow + base);    // in-bounds always (row cap MAXDEG)
            int se[4] = {e4.x, e4.y, e4.z, e4.w};
            float hs[4];
            if (LM == 0) {
                float xv[4];
                #pragma unroll
                for (int e = 0; e < 4; e++)
                    xv[e] = (e < ne) ? x[se[e] * FN_DIM + (lane & 15)] : 0.f;
                #pragma unroll
                for (int e = 0; e < 4; e++) {
                    float acc = sv[SV_BN + lane];
                    #pragma unroll
                    for (int k = 0; k < FN_DIM; k++) acc += __shfl(xv[e], k) * wN[k * HD + lane];
                    float vv = fmaxf(acc, 0.f);
                    float mu = wsum64(vv) * (1.f / 64.f);
                    float dd = vv - mu;
                    float var = wsum64(dd * dd) * (1.f / 64.f);
                    hs[e] = dd * rsqrtf(var + 1e-5f) * sv[SV_GN + lane] + sv[SV_BETAN + lane];
                }
            } else {
                #pragma unroll
                for (int e = 0; e < 4; e++)
                    hs[e] = (e < ne) ? hin[se[e] * HD + lane] : 0.f;
            }
            // attention logits (full-wave broadcast)
            float le[4];
            #pragma unroll
            for (int e = 0; e < 4; e++)
                le[e] = lrelu02(wsum64(hs[e] * sv[SV_PS + lane]) + a_dt);
            // v = Wc1b . h_s  (LDS weights, 4-edge batch)
            float v[4] = {0.f, 0.f, 0.f, 0.f};
            #pragma unroll 8
            for (int k = 0; k < HD; k++) {
                float wb = wB[k * HD + lane];
                #pragma unroll
                for (int e = 0; e < 4; e++) v[e] += __shfl(hs[e], k) * wb;
            }
            float hid[4], m[4];
            #pragma unroll
            for (int e = 0; e < 4; e++) { hid[e] = fmaxf(uval + v[e], 0.f); m[e] = sv[SV_BC2 + lane]; }
            #pragma unroll 8
            for (int k = 0; k < HD; k++) {
                float wc = wC[k * HD + lane];
                #pragma unroll
                for (int e = 0; e < 4; e++) m[e] += __shfl(hid[e], k) * wc;
            }
            #pragma unroll
            for (int e = 0; e < 4; e++) {
                if (e < ne) {
                    aggw = fmaxf(aggw, m[e]);
                    if (le[e] > mrun) {
                        float sc = expf(mrun - le[e]);   // exp(-inf)=0 first time
                        hw *= sc; wpart *= sc; mrun = le[e];
                    }
                    float we = expf(le[e] - mrun);
                    hw += we * hs[e]; wpart += we;
                }
            }
        }
        redA[wv][lane] = aggw;
        redH[wv][lane] = hw;
        if (lane == 0) { sM[wv] = mrun; sW[wv] = wpart; }
        __syncthreads();

        // ---- softmax merge (wave 0)
        if (wv == 0) {
            float M = es;
            #pragma unroll
            for (int q = 0; q < 4; q++) M = fmaxf(M, sM[q]);
            float den = expf(es - M);
            float num = den * hval;
            #pragma unroll
            for (int q = 0; q < 4; q++) {
                float sc = expf(sM[q] - M);     // 0 if that wave had no edges
                num += sc * redH[q][lane];
                den += sc * sW[q];
            }
            sHbar[lane] = num / den;
        }
        __syncthreads();

        // ---- att = Wg.hbar, k-split across waves (global Wg, 16 unrolled loads)
        float hb = sHbar[lane];
        float ap = 0.f;
        #pragma unroll
        for (int kk = 0; kk < 16; kk++) {
            int k = (wv << 4) + kk;
            ap += __shfl(hb, k) * Wg[k * HD + lane];
        }
        redU[wv][lane] = ap;
        __syncthreads();

        if (wv == 0) {
            float agg = fmaxf(fmaxf(redA[0][lane], redA[1][lane]),
                              fmaxf(redA[2][lane], redA[3][lane]));
            if (dg == 0) agg = 0.f;   // PyG scatter-max: empty segment -> 0
            float att = sv[SV_BG + lane] + redU[0][lane] + redU[1][lane]
                      + redU[2][lane] + redU[3][lane];
            float hv = fmaxf(hval + agg + att, 0.f);
            if (LM == 2) sHbar[lane] = hv;
            else hout[t * HD + lane] = hv;
        }

        if (LM == 2) {
            __syncthreads();
            float hvv = sHbar[lane];
            // k-split the two head matvecs: waves 0/1 -> q path, waves 2/3 -> v path
            float ap2 = 0.f;
            if (wv < 2) {
                #pragma unroll
                for (int kk = 0; kk < 32; kk++) {
                    int k = (wv << 5) + kk;
                    ap2 += __shfl(hvv, k) * Wq1[k * HD + lane];
                }
            } else {
                #pragma unroll
                for (int kk = 0; kk < 32; kk++) {
                    int k = ((wv - 2) << 5) + kk;
                    ap2 += __shfl(hvv, k) * Wv1[k * HD + lane];
                }
            }
            redU[wv][lane] = ap2;
            __syncthreads();
            if (wv == 0) {
                float acc = bq1[lane] + redU[0][lane] + redU[1][lane];
                float r = fmaxf(acc, 0.f);
                float mu = wsum64(r) * (1.f / 64.f);
                float d = r - mu;
                float var = wsum64(d * d) * (1.f / 64.f);
                float tq = d * rsqrtf(var + 1e-5f) * gq[lane] + betaq[lane];
                int s2 = lane & 31;
                float q = bq2[s2];
                #pragma unroll 16
                for (int k = 0; k < 64; k++) q += __shfl(tq, k) * Wq2[k * 32 + s2];
                if (lane < 32) hout[lane] = q;
            } else if (wv == 2) {
                float accv = bv1[lane] + redU[2][lane] + redU[3][lane];
                float rv = fmaxf(accv, 0.f);
                float muv = wsum64(rv) * (1.f / 64.f);
                float dv = rv - muv;
                float varv = wsum64(dv * dv) * (1.f / 64.f);
                float tv = dv * rsqrtf(varv + 1e-5f) * gv[lane] + betav[lane];
                float vs = wsum64(tv * Wv2[lane]);
                if (lane == 0) hout[32] = vs + bv2[0];
            }
        }
        __syncthreads();
    }
}

extern "C" void kernel_launch(void* const* d_in, const int* in_sizes, int n_in,
                              void* d_out, int out_size, void* d_ws, size_t ws_size,
                              hipStream_t stream) {
    const float* x        = (const float*)d_in[0];
    const int*   ei       = (const int*)d_in[1];
    // d_in[2] edge_attr and d_in[7..10] (edge encoder) are dead code in the reference
    const float* Wn       = (const float*)d_in[3];
    const float* bn       = (const float*)d_in[4];
    const float* gn       = (const float*)d_in[5];
    const float* betan    = (const float*)d_in[6];
    const float* Wc1      = (const float*)d_in[11];
    const float* bc1      = (const float*)d_in[12];
    const float* Wc2      = (const float*)d_in[13];
    const float* bc2      = (const float*)d_in[14];
    const float* Wg       = (const float*)d_in[15];
    const float* att_src  = (const float*)d_in[16];
    const float* att_dst  = (const float*)d_in[17];
    const float* bg       = (const float*)d_in[18];
    const float* Wq1      = (const float*)d_in[19];
    const float* bq1      = (const float*)d_in[20];
    const float* gq       = (const float*)d_in[21];
    const float* betaq    = (const float*)d_in[22];
    const float* Wq2      = (const float*)d_in[23];
    const float* bq2      = (const float*)d_in[24];
    const float* Wv1      = (const float*)d_in[25];
    const float* bv1      = (const float*)d_in[26];
    const float* gv       = (const float*)d_in[27];
    const float* betav    = (const float*)d_in[28];
    const float* Wv2      = (const float*)d_in[29];
    const float* bv2      = (const float*)d_in[30];

    // ---- workspace layout (~31 MB)
    float* hB   = (float*)d_ws;                      // h1, N*64
    float* hA   = hB + (size_t)N_NODES * HD;         // h2, N*64
    int* need1  = (int*)(hA + (size_t)N_NODES * HD); // zero-zone start (16B aligned)
    int* need2  = need1 + N_NODES;
    int* deg1   = need2 + N_NODES;                   // T_CAP
    int* deg2   = deg1 + T_CAP;                      // T2_CAP
    int* deg3   = deg2 + T2_CAP;                     // 4
    int* cnt    = deg3 + 4;                          // 8   (zero-zone end)
    int* idx1   = cnt + 8;                           // N
    int* idx2   = idx1 + N_NODES;                    // N
    int* list1  = idx2 + N_NODES;                    // T_CAP
    int* list2  = list1 + T_CAP;                     // T2_CAP
    int* eb1    = list2 + T2_CAP;                    // T_CAP*MAXDEG
    int* eb2    = eb1 + (size_t)T_CAP * MAXDEG;      // T2_CAP*MAXDEG
    int* eb3    = eb2 + (size_t)T2_CAP * MAXDEG;     // MAXDEG
    float* pvec = (float*)(eb3 + MAXDEG);            // 3*128 ps/pd vectors

    const int zero_ints = 2 * N_NODES + T_CAP + T2_CAP + 12;   // /4 exact
    const int n4 = zero_ints / 4;
    const int E4B = (N_EDGES / 4 + 255) / 256;
    const int NB = (N_NODES + 255) / 256;

    k_zero<<<(n4 + 255) / 256, 256, 0, stream>>>((int4*)need1, n4);
    k_mark2<<<E4B, 256, 0, stream>>>(ei, need1, need2);
    k_mark1<<<E4B, 256, 0, stream>>>(ei, need2, need1);
    k_compact<<<NB, 256, 0, stream>>>(need1, need2, list1, list2, idx1, idx2, cnt,
                                      Wg, att_src, att_dst, pvec);
    k_bucket<<<E4B, 256, 0, stream>>>(ei, need1, need2, idx1, idx2,
                                      eb1, deg1, eb2, deg2, eb3, deg3);

    // layer 0: targets list1 (~355), sources encoded from x on the fly -> hB
    k_layer<0><<<256, 256, 0, stream>>>(
        x, Wn, bn, gn, betan, (const float*)nullptr,
        Wc1 + 0 * 2 * HD * HD, bc1 + 0 * HD, Wc2 + 0 * HD * HD, bc2 + 0 * HD,
        Wg + 0 * HD * HD, pvec + 0 * 128, bg + 0 * HD,
        list1, cnt + 0, T_CAP, eb1, deg1, hB,
        Wq1, bq1, gq, betaq, Wq2, bq2, Wv1, bv1, gv, betav, Wv2, bv2);

    // layer 1: targets list2 (~17), h from hB -> hA
    k_layer<1><<<32, 256, 0, stream>>>(
        x, Wn, bn, gn, betan, hB,
        Wc1 + 1 * 2 * HD * HD, bc1 + 1 * HD, Wc2 + 1 * HD * HD, bc2 + 1 * HD,
        Wg + 1 * HD * HD, pvec + 1 * 128, bg + 1 * HD,
        list2, cnt + 1, T2_CAP, eb2, deg2, hA,
        Wq1, bq1, gq, betaq, Wq2, bq2, Wv1, bv1, gv, betav, Wv2, bv2);

    // layer 2: target {0}, h from hA -> heads -> d_out
    k_layer<2><<<1, 256, 0, stream>>>(
        x, Wn, bn, gn, betan, hA,
        Wc1 + 2 * 2 * HD * HD, bc1 + 2 * HD, Wc2 + 2 * HD * HD, bc2 + 2 * HD,
        Wg + 2 * HD * HD, pvec + 2 * 128, bg + 2 * HD,
        (const int*)nullptr, cnt + 1, 1, eb3, deg3, (float*)d_out,
        Wq1, bq1, gq, betaq, Wq2, bq2, Wv1, bv1, gv, betav, Wv2, bv2);
}